// Round 9
// baseline (37471.643 us; speedup 1.0000x reference)
//
#include <hip/hip_runtime.h>
#include <math.h>

#define BB 64
#define TT 512
#define HH 512
#define KK 512
#define G3 1536
#define PEN 0.7f
#define NBLK 256
#define NTHR 1024
#define SLAB 32768               // 64*512 floats (one transposed activation slab)
#define WSTRIDE ((size_t)(G3 * KK))
#define INVP 64                  // invalidate period (steps); ring RS=96 > INVP+2

// ---------------------------------------------------------------------------
// bypass helpers (sc0 sc1 = MALL-coherent). Scalar asm only; float4 asm used
// ONLY as outputs (inputs unsupported by clang).
__device__ __forceinline__ void ld1b(float* d, const float* p) {
  asm volatile("global_load_dword %0, %1, off sc0 sc1" : "=v"(*d) : "v"(p));
}
__device__ __forceinline__ float4 ld4b(const float* p) {
  float4 r; asm volatile("global_load_dwordx4 %0, %1, off sc0 sc1" : "=v"(r) : "v"(p)); return r;
}
__device__ __forceinline__ void stwt1(float* p, float v) {
  asm volatile("global_store_dword %0, %1, off sc0 sc1" :: "v"(p), "v"(v) : "memory");
}
__device__ __forceinline__ void vwait0() {
  asm volatile("s_waitcnt vmcnt(0)" ::: "memory");
  __builtin_amdgcn_sched_barrier(0);
}
__device__ __forceinline__ unsigned umin2(unsigned a, unsigned b) { return a < b ? a : b; }
__device__ __forceinline__ void st_flag(unsigned* p, unsigned v) {
  __hip_atomic_store(p, v, __ATOMIC_RELAXED, __HIP_MEMORY_SCOPE_AGENT);
}
// wave0 polls all 256 block flags (monotonic epochs; stale -> re-poll)
__device__ __forceinline__ void poll_all(const unsigned* flags, unsigned ep) {
  const unsigned* p = flags + (threadIdx.x & 63) * 4;
  for (;;) {
    uint4 v; asm volatile("global_load_dwordx4 %0, %1, off sc0 sc1" : "=v"(v) : "v"(p));
    asm volatile("s_waitcnt vmcnt(0)" ::: "memory");
    unsigned mn = umin2(umin2(v.x, v.y), umin2(v.z, v.w));
    if (__all((int)(mn >= ep))) break;
    __builtin_amdgcn_s_sleep(2);
  }
}
__device__ __forceinline__ void poll8(const unsigned* flag8, unsigned ep) {
  const unsigned* p = flag8 + (threadIdx.x & 7);
  for (;;) {
    unsigned v; asm volatile("global_load_dword %0, %1, off sc0 sc1" : "=v"(v) : "v"(p));
    asm volatile("s_waitcnt vmcnt(0)" ::: "memory");
    if (__all((int)(v >= ep))) break;
    __builtin_amdgcn_s_sleep(2);
  }
}

// ---------------------------------------------------------------------------
// pre 1: xc[t][s] = sum_b x[b,t,:] . Wsel[s,512:] + B*bsel[s]
__global__ void k_pre_xc(const float* __restrict__ x, const float* __restrict__ Wsel,
                         const float* __restrict__ bsel, float* __restrict__ xc) {
  int t = blockIdx.x, tid = threadIdx.x;
  __shared__ float xs[512];
  __shared__ float a0[256], a1[256], a2[256];
  for (int i = tid; i < 512; i += 256) {
    float s = 0.f;
    const float* px = x + (size_t)t * KK + i;
    for (int b = 0; b < BB; ++b) s += px[(size_t)b * TT * KK];
    xs[i] = s;
  }
  __syncthreads();
  float c0 = 0.f, c1 = 0.f, c2 = 0.f;
  for (int i = tid; i < 512; i += 256) {
    float v = xs[i];
    c0 += v * Wsel[512 + i];
    c1 += v * Wsel[1024 + 512 + i];
    c2 += v * Wsel[2048 + 512 + i];
  }
  a0[tid] = c0; a1[tid] = c1; a2[tid] = c2;
  __syncthreads();
  for (int off = 128; off; off >>= 1) {
    if (tid < off) { a0[tid] += a0[tid + off]; a1[tid] += a1[tid + off]; a2[tid] += a2[tid + off]; }
    __syncthreads();
  }
  if (tid == 0) {
    xc[t * 4 + 0] = a0[0] + 64.f * bsel[0];
    xc[t * 4 + 1] = a1[0] + 64.f * bsel[1];
    xc[t * 4 + 2] = a2[0] + 64.f * bsel[2];
  }
}

// pre 2: wsum/bsum, zero zslab, stage xT slot 0, zero sync words.
// Plain stores: visible to next dispatch via kernel-boundary release/acquire.
__global__ void k_pre_misc(const float* __restrict__ Wlw, const float* __restrict__ blw,
                           const float* __restrict__ x,
                           float* __restrict__ wsum, float* __restrict__ bsumb,
                           float* __restrict__ zslab, float* __restrict__ xT0,
                           unsigned* __restrict__ flags, unsigned* __restrict__ flag8,
                           float* __restrict__ plog) {
  int gtid = blockIdx.x * 256 + threadIdx.x;   // 64 blocks * 256
  for (int i = gtid; i < SLAB; i += 64 * 256) zslab[i] = 0.f;
  for (int i = gtid; i < SLAB; i += 64 * 256) {
    int b = i >> 9, k = i & 511;
    xT0[(k >> 2) * 256 + b * 4 + (k & 3)] = x[(size_t)b * TT * KK + k];
  }
  if (blockIdx.x == 0) {
    int tid = threadIdx.x;
    if (tid < 256) flags[tid] = 0u;
    if (tid < 8) flag8[tid] = 0u;
    if (tid < 24) plog[tid] = 0.f;
    for (int h = tid; h < 512; h += 256) {
      float s = 0.f;
      for (int g = 0; g < 512; ++g) s += Wlw[(size_t)g * 512 + h];
      wsum[h] = s;
    }
    __shared__ float red[256];
    float s = 0.f;
    for (int i = tid; i < 512; i += 256) s += blw[i];
    red[tid] = s;
    __syncthreads();
    for (int off = 128; off; off >>= 1) {
      if (tid < off) red[tid] += red[tid + off];
      __syncthreads();
    }
    if (tid == 0) *bsumb = red[0];
  }
}

// ---------------------------------------------------------------------------
// One GRU layer. Block owns 2 j-cols x all 64 b; wave w = K-slice of 32;
// lane = b. Transposed slabs: element (b,k) at [(k>>2)*256 + b*4 + (k&3)].
// CACHED=1: plain loads (L2-served, compiler-scheduled). CACHED=0: bypass asm.
template<int CACHED>
__device__ __forceinline__ void do_layer(
    int tid, int w, int b, int j0, int lidx, int bid,
    const float* __restrict__ aT, const float* __restrict__ hT,
    const float* __restrict__ Wih, const float* __restrict__ Whh,
    const float* __restrict__ bih_l, const float* __restrict__ bhh_l,
    const float* __restrict__ wsum, const float* __restrict__ Wsel,
    float* __restrict__ houtT, float* __restrict__ outN, float* __restrict__ outN2,
    float* __restrict__ part, float* red, float* r2) {
  const int k0 = w << 5;
  const float* a4p = aT + ((k0 >> 2) << 8) + (b << 2);
  const float* h4p = hT + ((k0 >> 2) << 8) + (b << 2);
  const float* wi0r = Wih + (size_t)(j0 + 0) * KK + k0;
  const float* wi1r = Wih + (size_t)(j0 + 1) * KK + k0;
  const float* wi0z = Wih + (size_t)(512 + j0 + 0) * KK + k0;
  const float* wi1z = Wih + (size_t)(512 + j0 + 1) * KK + k0;
  const float* wi0n = Wih + (size_t)(1024 + j0 + 0) * KK + k0;
  const float* wi1n = Wih + (size_t)(1024 + j0 + 1) * KK + k0;
  const float* wh0r = Whh + (size_t)(j0 + 0) * KK + k0;
  const float* wh1r = Whh + (size_t)(j0 + 1) * KK + k0;
  const float* wh0z = Whh + (size_t)(512 + j0 + 0) * KK + k0;
  const float* wh1z = Whh + (size_t)(512 + j0 + 1) * KK + k0;
  const float* wh0n = Whh + (size_t)(1024 + j0 + 0) * KK + k0;
  const float* wh1n = Whh + (size_t)(1024 + j0 + 1) * KK + k0;
  float ai0r = 0.f, ai1r = 0.f, ai0z = 0.f, ai1z = 0.f, ai0n = 0.f, ai1n = 0.f;
  float ah0r = 0.f, ah1r = 0.f, ah0z = 0.f, ah1z = 0.f, ah0n = 0.f, ah1n = 0.f;
  float4 A[8], H[8];
  if (CACHED) {
#pragma unroll
    for (int i = 0; i < 8; ++i) {
      A[i] = *(const float4*)(a4p + (i << 8));
      H[i] = *(const float4*)(h4p + (i << 8));
    }
  } else {
#pragma unroll
    for (int i = 0; i < 8; ++i) {
      A[i] = ld4b(a4p + (i << 8));
      H[i] = ld4b(h4p + (i << 8));
    }
    vwait0();
  }
#pragma unroll
  for (int c = 0; c < 8; ++c) {
    const float4 a4 = A[c];
    const float4 h4 = H[c];
    float4 q;
#define DOTW(acc, ptr, vv) q = *(const float4*)((ptr) + c * 4); \
    acc += vv.x * q.x + vv.y * q.y + vv.z * q.z + vv.w * q.w;
    DOTW(ai0r, wi0r, a4) DOTW(ai1r, wi1r, a4)
    DOTW(ai0z, wi0z, a4) DOTW(ai1z, wi1z, a4)
    DOTW(ai0n, wi0n, a4) DOTW(ai1n, wi1n, a4)
    DOTW(ah0r, wh0r, h4) DOTW(ah1r, wh1r, h4)
    DOTW(ah0z, wh0z, h4) DOTW(ah1z, wh1z, h4)
    DOTW(ah0n, wh0n, h4) DOTW(ah1n, wh1n, h4)
#undef DOTW
  }
  // cross-wave K reduce: red[(w*64+b)*13 + i], stride 13 -> conflict-free
  {
    int rb = ((w << 6) + b) * 13;
    red[rb + 0] = ai0r; red[rb + 1] = ai0z; red[rb + 2] = ai0n;
    red[rb + 3] = ah0r; red[rb + 4] = ah0z; red[rb + 5] = ah0n;
    red[rb + 6] = ai1r; red[rb + 7] = ai1z; red[rb + 8] = ai1n;
    red[rb + 9] = ah1r; red[rb + 10] = ah1z; red[rb + 11] = ah1n;
  }
  __syncthreads();
  if (tid < 128) {
    int jl = tid >> 6, bb = tid & 63;
    int je = j0 + jl;
    float hpv;
    if (!CACHED) ld1b(&hpv, hT + ((je >> 2) << 8) + (bb << 2) + (je & 3));
    float sI0 = 0.f, sI1 = 0.f, sI2 = 0.f, sH0 = 0.f, sH1 = 0.f, sH2 = 0.f;
#pragma unroll
    for (int ww = 0; ww < 16; ++ww) {
      int o = ((ww << 6) + bb) * 13 + jl * 6;
      sI0 += red[o]; sI1 += red[o + 1]; sI2 += red[o + 2];
      sH0 += red[o + 3]; sH1 += red[o + 4]; sH2 += red[o + 5];
    }
    if (CACHED) hpv = hT[((je >> 2) << 8) + (bb << 2) + (je & 3)];
    else vwait0();
    float air = sI0 + bih_l[je],        ahr = sH0 + bhh_l[je];
    float aiz = sI1 + bih_l[je + 512],  ahz = sH1 + bhh_l[je + 512];
    float ain = sI2 + bih_l[je + 1024], ahn = sH2 + bhh_l[je + 1024];
    float rg = 1.f / (1.f + expf(-(air + ahr)));
    float zg = 1.f / (1.f + expf(-(aiz + ahz)));
    float ng = tanhf(ain + rg * ahn);
    float hv = (1.f - zg) * ng + zg * hpv;
    stwt1(houtT + ((je >> 2) << 8) + (bb << 2) + (je & 3), hv);
    if (outN) stwt1(outN + (size_t)bb * HH + je, hv);
    if (outN2) stwt1(outN2 + (size_t)bb * HH + je, hv);
    r2[jl * 256 + 0 * 64 + bb] = hv * wsum[je];
    r2[jl * 256 + 1 * 64 + bb] = hv * Wsel[je];
    r2[jl * 256 + 2 * 64 + bb] = hv * Wsel[1024 + je];
    r2[jl * 256 + 3 * 64 + bb] = hv * Wsel[2048 + je];
  }
  __syncthreads();
  if (tid < 64) {
    float* pb = part + ((size_t)bid << 9);
    stwt1(pb + lidx * 64 + tid,       r2[tid]       + r2[256 + tid]);
    stwt1(pb + 128 + lidx * 64 + tid, r2[64 + tid]  + r2[320 + tid]);
    stwt1(pb + 256 + lidx * 64 + tid, r2[128 + tid] + r2[384 + tid]);
    stwt1(pb + 384 + lidx * 64 + tid, r2[192 + tid] + r2[448 + tid]);
  }
}

// ---------------------------------------------------------------------------
template<int CACHED, int RS>
__global__ __launch_bounds__(NTHR, 4) void k_persist(
    const float* __restrict__ x,
    const float* __restrict__ Wih_first, const float* __restrict__ Wih_rest,
    const float* __restrict__ Whh,
    const float* __restrict__ bih, const float* __restrict__ bhh,
    const float* __restrict__ Wsel,
    const float* __restrict__ wsum, const float* __restrict__ bsumb,
    const float* __restrict__ xc, const float* __restrict__ zslab,
    float* __restrict__ xTr, float* __restrict__ h0Tr, float* __restrict__ h1Tr,
    float* __restrict__ part, float* __restrict__ plog,
    float* __restrict__ out,
    unsigned* __restrict__ flags, unsigned* __restrict__ flag8) {
  __shared__ float red[16 * 64 * 13];   // 52 KB wave partials / scratch
  __shared__ float r2[512];
  int tid = threadIdx.x, bid = blockIdx.x;
  int w = tid >> 6, b = tid & 63;
  int j0 = bid * 2;
  float p0 = PEN, p1 = 1.f, p2 = 1.f;   // penalty state, replicated (deterministic)
  int cur = 0;

  // entry invalidate: drop any stale/poisoned L1/L2 lines from prior replays
  if (tid == 0)
    (void)__hip_atomic_load(&flags[0], __ATOMIC_ACQUIRE, __HIP_MEMORY_SCOPE_AGENT);
  __syncthreads();
  float bs = *bsumb;

  for (int t = 0; t < TT; ++t) {
    int cs = t % RS;
    int ps = (t + RS - 1) % RS;
    const float* xcur = xTr + (size_t)cs * SLAB;
    float* xnxt = xTr + (size_t)((t + 1) % RS) * SLAB;
    const float* h0p = (t == 0) ? zslab : (h0Tr + (size_t)ps * SLAB);
    float* h0c = h0Tr + (size_t)cs * SLAB;
    const float* h1p = (t == 0) ? zslab : (h1Tr + (size_t)ps * SLAB);
    float* h1c = h1Tr + (size_t)cs * SLAB;

    if (t > 0) {
      // ---- router: wait for the 8 reducer logit-partials, then replicate ----
      if (tid < 64) poll8(flag8, (unsigned)t);
      __syncthreads();
      if (tid < 24) { float v; ld1b(&v, plog + tid); vwait0(); red[tid] = v; }
      __syncthreads();
      float l0 = xc[4 * t + 0], l1 = xc[4 * t + 1], l2 = xc[4 * t + 2];
#pragma unroll
      for (int r = 0; r < 8; ++r) {
        l0 += red[r * 3 + 0]; l1 += red[r * 3 + 1]; l2 += red[r * 3 + 2];
      }
      float m = fmaxf(l0, fmaxf(l1, l2));
      float e0 = expf(l0 - m), e1 = expf(l1 - m), e2 = expf(l2 - m);
      float Z = e0 + e1 + e2;
      float w0_ = e0 / Z * p0, w1_ = e1 / Z * p1, w2_ = e2 / Z * p2;
      cur = 0; float bb_ = w0_;
      if (w1_ > bb_) { bb_ = w1_; cur = 1; }
      if (w2_ > bb_) { bb_ = w2_; cur = 2; }
      p0 *= (cur == 0) ? PEN : 1.f;
      p1 *= (cur == 1) ? PEN : 1.f;
      p2 *= (cur == 2) ? PEN : 1.f;
      float mx = fmaxf(p0, fmaxf(p1, p2));
      p0 /= mx; p1 /= mx; p2 /= mx;
      __syncthreads();   // release red before layer reuse

      // ---- periodic L1/L2 invalidate (ring distance RS=96 > INVP=64) ----
      if (CACHED && (t & (INVP - 1)) == 0) {
        if (tid == 0)
          (void)__hip_atomic_load(&flags[0], __ATOMIC_ACQUIRE, __HIP_MEMORY_SCOPE_AGENT);
        __syncthreads();
      }
    }

    // ---- stage x[:, t+1, :] transposed into the xT ring (write-through) ----
    if (t + 1 < TT && tid < 128) {
      int idx = (bid << 7) + tid;
      int b2 = idx >> 9, k = idx & 511;
      stwt1(xnxt + ((k >> 2) << 8) + (b2 << 2) + (k & 3),
            x[(size_t)b2 * TT * KK + (size_t)(t + 1) * KK + k]);
    }

    // ---- layer 0 ----
    do_layer<CACHED>(tid, w, b, j0, 0, bid, xcur, h0p,
                     Wih_first + (size_t)cur * WSTRIDE,
                     Whh + (size_t)(cur * 2) * WSTRIDE,
                     bih + (size_t)(cur * 2) * G3, bhh + (size_t)(cur * 2) * G3,
                     wsum, Wsel, h0c, nullptr, nullptr, part, red, r2);
    __syncthreads();                    // drains this thread's write-through stores
    if (tid == 0) st_flag(&flags[bid], 2u * (unsigned)t + 1u);
    if (tid < 64) poll_all(flags, 2u * (unsigned)t + 1u);
    __syncthreads();

    // ---- layer 1 ----
    float* o2 = (t == TT - 1) ? (out + (size_t)TT * SLAB) : nullptr;
    do_layer<CACHED>(tid, w, b, j0, 1, bid, h0c, h1p,
                     Wih_rest + (size_t)cur * WSTRIDE,
                     Whh + (size_t)(cur * 2 + 1) * WSTRIDE,
                     bih + (size_t)(cur * 2 + 1) * G3, bhh + (size_t)(cur * 2 + 1) * G3,
                     wsum, Wsel, h1c, out + (size_t)t * SLAB, o2, part, red, r2);
    __syncthreads();
    if (tid == 0) st_flag(&flags[bid], 2u * (unsigned)t + 2u);

    // ---- 8 reducer blocks: part -> 3-float logit partials each ----
    if (bid < 8 && t + 1 < TT) {
      if (tid < 64) poll_all(flags, 2u * (unsigned)t + 2u);
      __syncthreads();
      if (tid < 512) {
        int idx = tid & 63, oct = tid >> 6;
        int g = idx >> 4, i = idx & 15;
        int col = g * 128 + bid * 16 + i;      // rows r=bid*16+i; cols {D,e0,e1,e2}
        const float* pb = part + ((size_t)(oct * 32) << 9) + col;
        float a[32];
#pragma unroll
        for (int q = 0; q < 32; ++q) ld1b(&a[q], pb + ((size_t)q << 9));
        vwait0();
        float s = 0.f;
#pragma unroll
        for (int q = 0; q < 32; ++q) s += a[q];
        red[(oct << 6) + idx] = s;
      }
      __syncthreads();
      if (tid < 64) {
        float tot = 0.f;
#pragma unroll
        for (int oc = 0; oc < 8; ++oc) tot += red[(oc << 6) + tid];
        red[512 + tid] = tot;
      }
      __syncthreads();
      if (tid == 0) {
        const float* tp = red + 512;           // [0..15]=D, [16..31]=e0, [32..47]=e1, [48..63]=e2
#pragma unroll
        for (int s_ = 0; s_ < 3; ++s_) {
          float acc = 0.f;
#pragma unroll
          for (int i = 0; i < 16; ++i) acc += (tp[i] + bs) * tp[(s_ + 1) * 16 + i];
          stwt1(plog + bid * 3 + s_, acc);
        }
        vwait0();
        st_flag(&flag8[bid], (unsigned)t + 1u);
      }
      __syncthreads();
    }
  }
}

// ---------------------------------------------------------------------------
extern "C" void kernel_launch(void* const* d_in, const int* in_sizes, int n_in,
                              void* d_out, int out_size, void* d_ws, size_t ws_size,
                              hipStream_t stream) {
  const float* x         = (const float*)d_in[0];
  const float* Wih_first = (const float*)d_in[1];
  const float* Wih_rest  = (const float*)d_in[2];
  const float* Whh       = (const float*)d_in[3];
  const float* bih       = (const float*)d_in[4];
  const float* bhh       = (const float*)d_in[5];
  const float* Wlw       = (const float*)d_in[6];
  const float* blw       = (const float*)d_in[7];
  const float* Wsel      = (const float*)d_in[8];
  const float* bsel      = (const float*)d_in[9];
  float* out = (float*)d_out;
  float* ws  = (float*)d_ws;

  float* xc       = ws;                       // 2048
  float* wsum     = ws + 2048;                // 512
  float* bsumb    = ws + 2560;                // 4
  float* plog     = ws + 2564;                // 24 (pad to 2592)
  unsigned* flags = (unsigned*)(ws + 2592);   // 256 (16B aligned)
  unsigned* flag8 = (unsigned*)(ws + 2848);   // 8
  float* part     = ws + 4096;                // 256*512 = 131072 -> 135168
  float* zslab    = ws + 135168;              // 32768 -> 167936
  float* rings    = ws + 167936;              // 3 rings x RS x SLAB

  size_t need_big = ((size_t)167936 + (size_t)3 * 96 * SLAB) * sizeof(float);

  k_pre_xc<<<dim3(TT), 256, 0, stream>>>(x, Wsel, bsel, xc);
  k_pre_misc<<<dim3(64), 256, 0, stream>>>(Wlw, blw, x, wsum, bsumb,
                                           zslab, rings, flags, flag8, plog);
  if (ws_size >= need_big) {
    float* xTr  = rings;
    float* h0Tr = rings + (size_t)96 * SLAB;
    float* h1Tr = rings + (size_t)192 * SLAB;
    k_persist<1, 96><<<dim3(NBLK), NTHR, 0, stream>>>(
        x, Wih_first, Wih_rest, Whh, bih, bhh, Wsel, wsum, bsumb, xc, zslab,
        xTr, h0Tr, h1Tr, part, plog, out, flags, flag8);
  } else {
    float* xTr  = rings;
    float* h0Tr = rings + (size_t)2 * SLAB;
    float* h1Tr = rings + (size_t)4 * SLAB;
    k_persist<0, 2><<<dim3(NBLK), NTHR, 0, stream>>>(
        x, Wih_first, Wih_rest, Whh, bih, bhh, Wsel, wsum, bsumb, xc, zslab,
        xTr, h0Tr, h1Tr, part, plog, out, flags, flag8);
  }
}

// Round 10
// 17878.995 us; speedup vs baseline: 2.0958x; 2.0958x over previous
//
#include <hip/hip_runtime.h>
#include <math.h>

#define BB 64
#define TT 512
#define HH 512
#define KK 512
#define G3 1536
#define PEN 0.7f
#define NBLK 256
#define NTHR 512
#define SLAB 32768               // 64*512 floats (one transposed activation slab)
#define WSTRIDE ((size_t)(G3 * KK))

// ---------------------------------------------------------------------------
// sc0 sc1 = bypass L1+L2 (MALL-coherent). sc0 only = bypass L1, cache in L2.
__device__ __forceinline__ float4 ld4b(const float* p) {
  float4 r; asm volatile("global_load_dwordx4 %0, %1, off sc0 sc1" : "=v"(r) : "v"(p)); return r;
}
__device__ __forceinline__ float4 ld4s(const float* p) {
  float4 r; asm volatile("global_load_dwordx4 %0, %1, off sc0" : "=v"(r) : "v"(p)); return r;
}
__device__ __forceinline__ void ld1b(float* d, const float* p) {
  asm volatile("global_load_dword %0, %1, off sc0 sc1" : "=v"(*d) : "v"(p));
}
__device__ __forceinline__ void ld1s(float* d, const float* p) {
  asm volatile("global_load_dword %0, %1, off sc0" : "=v"(*d) : "v"(p));
}
__device__ __forceinline__ void stwt1(float* p, float v) {
  asm volatile("global_store_dword %0, %1, off sc0 sc1" :: "v"(p), "v"(v) : "memory");
}
__device__ __forceinline__ void vwait0() {
  asm volatile("s_waitcnt vmcnt(0)" ::: "memory");
  __builtin_amdgcn_sched_barrier(0);
}
__device__ __forceinline__ unsigned umin2(unsigned a, unsigned b) { return a < b ? a : b; }
__device__ __forceinline__ void st_flag(unsigned* p, unsigned v) {
  __hip_atomic_store(p, v, __ATOMIC_RELAXED, __HIP_MEMORY_SCOPE_AGENT);
}
__device__ __forceinline__ void poll_all(const unsigned* flags, unsigned ep) {
  const unsigned* p = flags + (threadIdx.x & 63) * 4;
  for (;;) {
    uint4 v; asm volatile("global_load_dwordx4 %0, %1, off sc0 sc1" : "=v"(v) : "v"(p));
    asm volatile("s_waitcnt vmcnt(0)" ::: "memory");
    unsigned mn = umin2(umin2(v.x, v.y), umin2(v.z, v.w));
    if (__all((int)(mn >= ep))) break;
    __builtin_amdgcn_s_sleep(2);
  }
}
__device__ __forceinline__ void poll8(const unsigned* flag8, unsigned ep) {
  const unsigned* p = flag8 + (threadIdx.x & 7);
  for (;;) {
    unsigned v; asm volatile("global_load_dword %0, %1, off sc0 sc1" : "=v"(v) : "v"(p));
    asm volatile("s_waitcnt vmcnt(0)" ::: "memory");
    if (__all((int)(v >= ep))) break;
    __builtin_amdgcn_s_sleep(2);
  }
}

// ---------------------------------------------------------------------------
// pre 1: xc[t][s] = sum_b x[b,t,:] . Wsel[s,512:] + B*bsel[s]
__global__ void k_pre_xc(const float* __restrict__ x, const float* __restrict__ Wsel,
                         const float* __restrict__ bsel, float* __restrict__ xc) {
  int t = blockIdx.x, tid = threadIdx.x;
  __shared__ float xs[512];
  __shared__ float a0[256], a1[256], a2[256];
  for (int i = tid; i < 512; i += 256) {
    float s = 0.f;
    const float* px = x + (size_t)t * KK + i;
    for (int b = 0; b < BB; ++b) s += px[(size_t)b * TT * KK];
    xs[i] = s;
  }
  __syncthreads();
  float c0 = 0.f, c1 = 0.f, c2 = 0.f;
  for (int i = tid; i < 512; i += 256) {
    float v = xs[i];
    c0 += v * Wsel[512 + i];
    c1 += v * Wsel[1024 + 512 + i];
    c2 += v * Wsel[2048 + 512 + i];
  }
  a0[tid] = c0; a1[tid] = c1; a2[tid] = c2;
  __syncthreads();
  for (int off = 128; off; off >>= 1) {
    if (tid < off) { a0[tid] += a0[tid + off]; a1[tid] += a1[tid + off]; a2[tid] += a2[tid + off]; }
    __syncthreads();
  }
  if (tid == 0) {
    xc[t * 4 + 0] = a0[0] + 64.f * bsel[0];
    xc[t * 4 + 1] = a1[0] + 64.f * bsel[1];
    xc[t * 4 + 2] = a2[0] + 64.f * bsel[2];
  }
}

// pre 2: wsum/bsum, zero zslab, stage x[:,0,:] transposed into xT slot 0
// (small mode), zero sync words. Plain stores: visible to next dispatch.
__global__ void k_pre_misc(const float* __restrict__ Wlw, const float* __restrict__ blw,
                           const float* __restrict__ x,
                           float* __restrict__ wsum, float* __restrict__ bsumb,
                           float* __restrict__ zslab, float* __restrict__ xT0,
                           unsigned* __restrict__ flags, unsigned* __restrict__ flag8,
                           float* __restrict__ partial2) {
  int gtid = blockIdx.x * 256 + threadIdx.x;   // 64 blocks * 256
  for (int i = gtid; i < SLAB; i += 64 * 256) zslab[i] = 0.f;
  for (int i = gtid; i < SLAB; i += 64 * 256) {
    int b = i >> 9, k = i & 511;
    xT0[(k >> 2) * 256 + b * 4 + (k & 3)] = x[(size_t)b * TT * KK + k];
  }
  if (blockIdx.x == 0) {
    int tid = threadIdx.x;
    if (tid < 256) flags[tid] = 0u;
    if (tid < 8) flag8[tid] = 0u;
    for (int i = tid; i < 8 * 512; i += 256) partial2[i] = 0.f;
    for (int h = tid; h < 512; h += 256) {
      float s = 0.f;
      for (int g = 0; g < 512; ++g) s += Wlw[(size_t)g * 512 + h];
      wsum[h] = s;
    }
    __shared__ float red[256];
    float s = 0.f;
    for (int i = tid; i < 512; i += 256) s += blw[i];
    red[tid] = s;
    __syncthreads();
    for (int off = 128; off; off >>= 1) {
      if (tid < off) red[tid] += red[tid + off];
      __syncthreads();
    }
    if (tid == 0) *bsumb = red[0];
  }
}

// ---------------------------------------------------------------------------
// One GRU layer. Block owns 2 j-cols x all 64 b; wave w = K-slice of 64;
// lane = b. Transposed slabs: (b,k) at [(k>>2)*256 + b*4 + (k&3)].
// AM/HM: 0 = bypass(transposed), 1 = sc0 L2-cached(transposed, write-once ring),
//        2 = plain cached strided (x direct, read-only).
template<int AM, int HM>
__device__ __forceinline__ void do_layer(
    int tid, int b, int k0, int j0, int lidx, int bid,
    const float* __restrict__ abase, size_t astride,
    const float* __restrict__ hT,
    const float* __restrict__ Wih, const float* __restrict__ Whh,
    const float* __restrict__ bih_l, const float* __restrict__ bhh_l,
    const float* __restrict__ wsum, const float* __restrict__ Wsel,
    float* __restrict__ houtT, float* __restrict__ outN, float* __restrict__ outN2,
    float* __restrict__ part, float* red, float* r2) {
  const float* aB = (AM == 2) ? (abase + (size_t)b * astride + k0)
                              : (abase + ((k0 >> 2) << 8) + (b << 2));
  const float* hB = hT + ((k0 >> 2) << 8) + (b << 2);
  const float* wi0r = Wih + (size_t)(j0 + 0) * KK + k0;
  const float* wi1r = Wih + (size_t)(j0 + 1) * KK + k0;
  const float* wi0z = Wih + (size_t)(512 + j0 + 0) * KK + k0;
  const float* wi1z = Wih + (size_t)(512 + j0 + 1) * KK + k0;
  const float* wi0n = Wih + (size_t)(1024 + j0 + 0) * KK + k0;
  const float* wi1n = Wih + (size_t)(1024 + j0 + 1) * KK + k0;
  const float* wh0r = Whh + (size_t)(j0 + 0) * KK + k0;
  const float* wh1r = Whh + (size_t)(j0 + 1) * KK + k0;
  const float* wh0z = Whh + (size_t)(512 + j0 + 0) * KK + k0;
  const float* wh1z = Whh + (size_t)(512 + j0 + 1) * KK + k0;
  const float* wh0n = Whh + (size_t)(1024 + j0 + 0) * KK + k0;
  const float* wh1n = Whh + (size_t)(1024 + j0 + 1) * KK + k0;
  float ai0r = 0.f, ai1r = 0.f, ai0z = 0.f, ai1z = 0.f, ai0n = 0.f, ai1n = 0.f;
  float ah0r = 0.f, ah1r = 0.f, ah0z = 0.f, ah1z = 0.f, ah0n = 0.f, ah1n = 0.f;
  float4 A[8], H[8];
  for (int half = 0; half < 2; ++half) {
#pragma unroll
    for (int i = 0; i < 8; ++i) {
      if (AM == 2)      A[i] = *(const float4*)(aB + half * 32 + i * 4);
      else if (AM == 1) A[i] = ld4s(aB + half * 2048 + (i << 8));
      else              A[i] = ld4b(aB + half * 2048 + (i << 8));
      if (HM == 1)      H[i] = ld4s(hB + half * 2048 + (i << 8));
      else              H[i] = ld4b(hB + half * 2048 + (i << 8));
    }
    vwait0();
#pragma unroll
    for (int c = 0; c < 8; ++c) {
      const int kc = half * 8 + c;
      const float4 a4 = A[c];
      const float4 h4 = H[c];
      float4 q;
#define DOTW(acc, ptr, vv) q = *(const float4*)((ptr) + kc * 4); \
      acc += vv.x * q.x + vv.y * q.y + vv.z * q.z + vv.w * q.w;
      DOTW(ai0r, wi0r, a4) DOTW(ai1r, wi1r, a4)
      DOTW(ai0z, wi0z, a4) DOTW(ai1z, wi1z, a4)
      DOTW(ai0n, wi0n, a4) DOTW(ai1n, wi1n, a4)
      DOTW(ah0r, wh0r, h4) DOTW(ah1r, wh1r, h4)
      DOTW(ah0z, wh0z, h4) DOTW(ah1z, wh1z, h4)
      DOTW(ah0n, wh0n, h4) DOTW(ah1n, wh1n, h4)
#undef DOTW
    }
  }
  int w = tid >> 6;
  int base = (w * 12) * 64 + b;
  red[base + 0 * 64] = ai0r; red[base + 1 * 64] = ai0z; red[base + 2 * 64] = ai0n;
  red[base + 3 * 64] = ah0r; red[base + 4 * 64] = ah0z; red[base + 5 * 64] = ah0n;
  red[base + 6 * 64] = ai1r; red[base + 7 * 64] = ai1z; red[base + 8 * 64] = ai1n;
  red[base + 9 * 64] = ah1r; red[base + 10 * 64] = ah1z; red[base + 11 * 64] = ah1n;
  __syncthreads();
  if (tid < 128) {
    int bb = tid & 63, jl = tid >> 6;
    int je = j0 + jl;
    float hpv;
    if (HM == 1) ld1s(&hpv, hT + ((je >> 2) << 8) + (bb << 2) + (je & 3));
    else         ld1b(&hpv, hT + ((je >> 2) << 8) + (bb << 2) + (je & 3));
    float sir = 0.f, siz = 0.f, sinn = 0.f, shr = 0.f, shz = 0.f, shn = 0.f;
#pragma unroll
    for (int ww = 0; ww < 8; ++ww) {
      int o = (ww * 12 + jl * 6) * 64 + bb;
      sir += red[o]; siz += red[o + 64]; sinn += red[o + 128];
      shr += red[o + 192]; shz += red[o + 256]; shn += red[o + 320];
    }
    vwait0();
    float air = sir + bih_l[je],         ahr = shr + bhh_l[je];
    float aiz = siz + bih_l[je + 512],   ahz = shz + bhh_l[je + 512];
    float ain = sinn + bih_l[je + 1024], ahn = shn + bhh_l[je + 1024];
    float rg = 1.f / (1.f + expf(-(air + ahr)));
    float zg = 1.f / (1.f + expf(-(aiz + ahz)));
    float ng = tanhf(ain + rg * ahn);
    float hv = (1.f - zg) * ng + zg * hpv;
    stwt1(houtT + ((je >> 2) << 8) + (bb << 2) + (je & 3), hv);
    if (outN) stwt1(outN + (size_t)bb * HH + je, hv);
    if (outN2) stwt1(outN2 + (size_t)bb * HH + je, hv);
    r2[jl * 256 + 0 * 64 + bb] = hv * wsum[je];
    r2[jl * 256 + 1 * 64 + bb] = hv * Wsel[je];
    r2[jl * 256 + 2 * 64 + bb] = hv * Wsel[1024 + je];
    r2[jl * 256 + 3 * 64 + bb] = hv * Wsel[2048 + je];
  }
  __syncthreads();
  if (tid < 64) {
    float* pb = part + ((size_t)bid << 9);
    stwt1(pb + lidx * 64 + tid,       r2[tid]       + r2[256 + tid]);
    stwt1(pb + 128 + lidx * 64 + tid, r2[64 + tid]  + r2[320 + tid]);
    stwt1(pb + 256 + lidx * 64 + tid, r2[128 + tid] + r2[384 + tid]);
    stwt1(pb + 384 + lidx * 64 + tid, r2[192 + tid] + r2[448 + tid]);
  }
}

// ---------------------------------------------------------------------------
// BIG=1: rA/rB are 512-slab write-once h0/h1 rings (sc0 reads, L2-shared);
//        x read direct (plain cached, read-only).
// BIG=0: round-6 mode: rA=xT(2 slots), rB=h0T(2), rC=h1T(2), all bypass.
template<int BIG>
__global__ __launch_bounds__(NTHR, 2) void k_persist(
    const float* __restrict__ x,
    const float* __restrict__ Wih_first, const float* __restrict__ Wih_rest,
    const float* __restrict__ Whh,
    const float* __restrict__ bih, const float* __restrict__ bhh,
    const float* __restrict__ Wsel,
    const float* __restrict__ wsum, const float* __restrict__ bsumb,
    const float* __restrict__ xc, const float* __restrict__ zslab,
    float* __restrict__ rA, float* __restrict__ rB, float* __restrict__ rC,
    float* __restrict__ part, float* __restrict__ partial2,
    float* __restrict__ out,
    unsigned* __restrict__ flags, unsigned* __restrict__ flag8) {
  __shared__ float red[8 * 12 * 64];   // 24 KB
  __shared__ float r2[512];
  int tid = threadIdx.x, bid = blockIdx.x;
  int b = tid & 63;
  int k0 = __builtin_amdgcn_readfirstlane(((int)threadIdx.x >> 6) << 6);
  int j0 = bid * 2;
  float p0 = PEN, p1 = 1.f, p2 = 1.f;
  int cur = 0;

  // single entry acquire: drop any lines cached before this launch
  if (tid == 0)
    (void)__hip_atomic_load(&flags[0], __ATOMIC_ACQUIRE, __HIP_MEMORY_SCOPE_AGENT);
  __syncthreads();
  float bs = *bsumb;

  for (int t = 0; t < TT; ++t) {
    const float *aL0, *h0rd, *h1rd;
    float *h0wr, *h1wr, *xnxt = nullptr;
    size_t aStr;
    if (BIG) {
      aL0 = x + (size_t)t * KK;           aStr = (size_t)TT * KK;
      h0rd = t ? (rA + (size_t)(t - 1) * SLAB) : zslab;
      h0wr = rA + (size_t)t * SLAB;
      h1rd = t ? (rB + (size_t)(t - 1) * SLAB) : zslab;
      h1wr = rB + (size_t)t * SLAB;
    } else {
      int par = t & 1;
      aL0 = rA + (size_t)par * SLAB;      aStr = 0;
      xnxt = rA + (size_t)(par ^ 1) * SLAB;
      h0rd = t ? (rB + (size_t)((t - 1) & 1) * SLAB) : zslab;
      h0wr = rB + (size_t)(t & 1) * SLAB;
      h1rd = t ? (rC + (size_t)((t - 1) & 1) * SLAB) : zslab;
      h1wr = rC + (size_t)(t & 1) * SLAB;
    }

    if (t > 0) {
      // ---- router (replicated per block, deterministic) ----
      if (tid < 64) poll8(flag8, (unsigned)t);
      __syncthreads();
      float g0, g1, g2, g3, g4, g5, g6, g7;
      ld1b(&g0, partial2 + 0 * 512 + tid);
      ld1b(&g1, partial2 + 1 * 512 + tid);
      ld1b(&g2, partial2 + 2 * 512 + tid);
      ld1b(&g3, partial2 + 3 * 512 + tid);
      ld1b(&g4, partial2 + 4 * 512 + tid);
      ld1b(&g5, partial2 + 5 * 512 + tid);
      ld1b(&g6, partial2 + 6 * 512 + tid);
      ld1b(&g7, partial2 + 7 * 512 + tid);
      vwait0();
      red[tid] = ((g0 + g1) + (g2 + g3)) + ((g4 + g5) + (g6 + g7));
      __syncthreads();
      float prod = 0.f;
      if (tid < 384) {
        int s = tid >> 7, row = tid & 127;
        prod = (red[row] + bs) * red[128 + (s << 7) + row];
      }
#pragma unroll
      for (int off = 1; off < 64; off <<= 1) prod += __shfl_xor(prod, off);
      if ((tid & 63) == 0) r2[tid >> 6] = prod;
      __syncthreads();
      float l0 = r2[0] + r2[1] + xc[t * 4 + 0];
      float l1 = r2[2] + r2[3] + xc[t * 4 + 1];
      float l2 = r2[4] + r2[5] + xc[t * 4 + 2];
      float m = fmaxf(l0, fmaxf(l1, l2));
      float e0 = expf(l0 - m), e1 = expf(l1 - m), e2 = expf(l2 - m);
      float Z = e0 + e1 + e2;
      float w0_ = e0 / Z * p0, w1_ = e1 / Z * p1, w2_ = e2 / Z * p2;
      cur = 0; float bb_ = w0_;
      if (w1_ > bb_) { bb_ = w1_; cur = 1; }
      if (w2_ > bb_) { bb_ = w2_; cur = 2; }
      p0 *= (cur == 0) ? PEN : 1.f;
      p1 *= (cur == 1) ? PEN : 1.f;
      p2 *= (cur == 2) ? PEN : 1.f;
      float mx = fmaxf(p0, fmaxf(p1, p2));
      p0 /= mx; p1 /= mx; p2 /= mx;
      __syncthreads();   // release red/r2 before layer reuse
    }

    // ---- small mode: stage x[:, t+1, :] transposed (write-through) ----
    if (!BIG && t + 1 < TT && tid < 128) {
      int idx = (bid << 7) + tid;
      int b2 = idx >> 9, k = idx & 511;
      stwt1(xnxt + ((k >> 2) << 8) + (b2 << 2) + (k & 3),
            x[(size_t)b2 * TT * KK + (size_t)(t + 1) * KK + k]);
    }

    // ---- layer 0 ----
    do_layer<BIG ? 2 : 0, BIG ? 1 : 0>(tid, b, k0, j0, 0, bid, aL0, aStr, h0rd,
        Wih_first + (size_t)cur * WSTRIDE,
        Whh + (size_t)(cur * 2) * WSTRIDE,
        bih + (size_t)(cur * 2) * G3, bhh + (size_t)(cur * 2) * G3,
        wsum, Wsel, h0wr, nullptr, nullptr, part, red, r2);
    __syncthreads();
    if (tid == 0) st_flag(&flags[bid], 2u * (unsigned)t + 1u);
    if (tid < 64) poll_all(flags, 2u * (unsigned)t + 1u);
    __syncthreads();

    // ---- layer 1 ----
    float* o2 = (t == TT - 1) ? (out + (size_t)TT * SLAB) : nullptr;
    do_layer<BIG ? 1 : 0, BIG ? 1 : 0>(tid, b, k0, j0, 1, bid, h0wr, (size_t)0, h1rd,
        Wih_rest + (size_t)cur * WSTRIDE,
        Whh + (size_t)(cur * 2 + 1) * WSTRIDE,
        bih + (size_t)(cur * 2 + 1) * G3, bhh + (size_t)(cur * 2 + 1) * G3,
        wsum, Wsel, h1wr, out + (size_t)t * SLAB, o2, part, red, r2);
    __syncthreads();
    if (tid == 0) st_flag(&flags[bid], 2u * (unsigned)t + 2u);

    // ---- 8 reducer blocks: part -> partial2 for next step's router ----
    if (bid < 8 && t + 1 < TT) {
      if (tid < 64) poll_all(flags, 2u * (unsigned)t + 2u);
      __syncthreads();
      float a[32];
#pragma unroll
      for (int r = 0; r < 32; ++r)
        ld1b(&a[r], part + (size_t)(32 * bid + r) * 512 + tid);
      vwait0();
      float s = 0.f;
#pragma unroll
      for (int r = 0; r < 32; ++r) s += a[r];
      stwt1(partial2 + bid * 512 + tid, s);
      vwait0();
      __syncthreads();
      if (tid == 0) st_flag(&flag8[bid], (unsigned)t + 1u);
    }
  }
}

// ---------------------------------------------------------------------------
extern "C" void kernel_launch(void* const* d_in, const int* in_sizes, int n_in,
                              void* d_out, int out_size, void* d_ws, size_t ws_size,
                              hipStream_t stream) {
  const float* x         = (const float*)d_in[0];
  const float* Wih_first = (const float*)d_in[1];
  const float* Wih_rest  = (const float*)d_in[2];
  const float* Whh       = (const float*)d_in[3];
  const float* bih       = (const float*)d_in[4];
  const float* bhh       = (const float*)d_in[5];
  const float* Wlw       = (const float*)d_in[6];
  const float* blw       = (const float*)d_in[7];
  const float* Wsel      = (const float*)d_in[8];
  const float* bsel      = (const float*)d_in[9];
  float* out = (float*)d_out;
  float* ws  = (float*)d_ws;

  float* xc       = ws;                       // 2048
  float* wsum     = ws + 2048;                // 512
  float* bsumb    = ws + 2560;                // 4
  unsigned* flags = (unsigned*)(ws + 2592);   // 256 (16B aligned)
  unsigned* flag8 = (unsigned*)(ws + 2848);   // 8
  float* partial2 = ws + 2880;                // 8*512 = 4096 -> 6976 (pad to 8192)
  float* part     = ws + 8192;                // 256*512 = 131072 -> 139264
  float* zslab    = ws + 139264;              // 32768 -> 172032
  float* rings    = ws + 172032;              // BIG: 2x512 slabs; SMALL: 3x2 slabs

  size_t need_big = ((size_t)172032 + (size_t)1024 * SLAB) * sizeof(float);
  int big = (ws_size >= need_big);

  k_pre_xc<<<dim3(TT), 256, 0, stream>>>(x, Wsel, bsel, xc);
  // xT0 (slot-0 staging) is only meaningful in SMALL; in BIG it lands in the
  // h0 ring slot 0, which is overwritten (via MALL) at t=0 before first read.
  k_pre_misc<<<dim3(64), 256, 0, stream>>>(Wlw, blw, x, wsum, bsumb,
                                           zslab, rings, flags, flag8, partial2);
  if (big) {
    float* h0R = rings;
    float* h1R = rings + (size_t)512 * SLAB;
    k_persist<1><<<dim3(NBLK), NTHR, 0, stream>>>(
        x, Wih_first, Wih_rest, Whh, bih, bhh, Wsel, wsum, bsumb, xc, zslab,
        h0R, h1R, nullptr, part, partial2, out, flags, flag8);
  } else {
    float* xT  = rings;
    float* h0T = rings + (size_t)2 * SLAB;
    float* h1T = rings + (size_t)4 * SLAB;
    k_persist<0><<<dim3(NBLK), NTHR, 0, stream>>>(
        x, Wih_first, Wih_rest, Whh, bih, bhh, Wsel, wsum, bsumb, xc, zslab,
        xT, h0T, h1T, part, partial2, out, flags, flag8);
  }
}